// Round 4
// baseline (170.887 us; speedup 1.0000x reference)
//
#include <hip/hip_runtime.h>
#include <math.h>

#define IMG  512
#define TW   32
#define TH   32
#define EXTR 42          // TH + 10 haloed rows
#define HS   33          // hb stride: h-writes & v-reads <=2-way bank alias
#define NPIX 12582912.0  // 48*512*512

// Normalized 11-tap Gaussian, sigma=1.5 — inline literals
constexpr float G[11] = {
    0.00102838f, 0.00759876f, 0.03600077f, 0.10936069f, 0.21300554f,
    0.26601173f,
    0.21300554f, 0.10936069f, 0.03600077f, 0.00759876f, 0.00102838f};

// hb planes: 0=mean(x) 1=mean(y) 2=mean(x^2+y^2) 3=mean(xy)
__global__ __launch_bounds__(384) void ssim_tile_kernel(
    const float* __restrict__ x, const float* __restrict__ y,
    double* __restrict__ acc)
{
    __shared__ float hb[4][EXTR][HS];   // 21.66 KB -> 5 blocks/CU (wave cap)
    __shared__ float wsum[6];

    const int tid = threadIdx.x;
    const int bx = blockIdx.x, by = blockIdx.y;
    const int c0 = bx * TW, r0 = by * TH;
    const size_t ioff = (size_t)blockIdx.z * IMG * IMG;
    const float* __restrict__ xb = x + ioff;
    const float* __restrict__ yb = y + ioff;

    const bool interior = (bx > 0) & (bx < 15) & (by > 0) & (by < 15);

    // ---- horizontal pass: 42 rows x 8 groups = 336 tasks, ONE per thread ----
    if (tid < EXTR * 8) {
        const int row = tid >> 3;       // 0..41
        const int g   = tid & 7;        // 4-output col group
        const int gr  = r0 - 5 + row;
        const int gc0 = c0 - 8 + 4 * g; // first of 20 raw cols
        float wx[20], wy[20];
        if (interior) {
            const float* __restrict__ px = xb + gr * IMG + gc0;
            const float* __restrict__ py = yb + gr * IMG + gc0;
#pragma unroll
            for (int i = 0; i < 5; ++i) {
                float4 fx = *(const float4*)(px + 4 * i);
                float4 fy = *(const float4*)(py + 4 * i);
                wx[4*i+0] = fx.x; wx[4*i+1] = fx.y; wx[4*i+2] = fx.z; wx[4*i+3] = fx.w;
                wy[4*i+0] = fy.x; wy[4*i+1] = fy.y; wy[4*i+2] = fy.z; wy[4*i+3] = fy.w;
            }
        } else {
            const bool rok = ((unsigned)gr < IMG);
            const float* __restrict__ px = xb + gr * IMG;
            const float* __restrict__ py = yb + gr * IMG;
#pragma unroll
            for (int i = 0; i < 5; ++i) {
                int gc = gc0 + 4 * i;
                if (rok && gc >= 0 && gc + 3 < IMG) {
                    float4 fx = *(const float4*)(px + gc);
                    float4 fy = *(const float4*)(py + gc);
                    wx[4*i+0] = fx.x; wx[4*i+1] = fx.y; wx[4*i+2] = fx.z; wx[4*i+3] = fx.w;
                    wy[4*i+0] = fy.x; wy[4*i+1] = fy.y; wy[4*i+2] = fy.z; wy[4*i+3] = fy.w;
                } else {
#pragma unroll
                    for (int e = 0; e < 4; ++e) {
                        int c = gc + e;
                        bool ok = rok && ((unsigned)c < IMG);
                        wx[4*i+e] = ok ? px[c] : 0.f;
                        wy[4*i+e] = ok ? py[c] : 0.f;
                    }
                }
            }
        }
        // shared products for raw cols 3..16
        float pss[14], pxy[14];
#pragma unroll
        for (int j = 0; j < 14; ++j) {
            float a = wx[j + 3], b = wy[j + 3];
            pss[j] = fmaf(a, a, b * b);
            pxy[j] = a * b;
        }
        float ax[4] = {}, ay[4] = {}, ass[4] = {}, axy[4] = {};
#pragma unroll
        for (int e = 0; e < 4; ++e)
#pragma unroll
            for (int k = 0; k < 11; ++k) {
                ax[e]  = fmaf(G[k], wx[e + k + 3], ax[e]);
                ay[e]  = fmaf(G[k], wy[e + k + 3], ay[e]);
                ass[e] = fmaf(G[k], pss[e + k], ass[e]);
                axy[e] = fmaf(G[k], pxy[e + k], axy[e]);
            }
#pragma unroll
        for (int e = 0; e < 4; ++e) {
            int cc = 4 * g + e;
            hb[0][row][cc] = ax[e];
            hb[1][row][cc] = ay[e];
            hb[2][row][cc] = ass[e];
            hb[3][row][cc] = axy[e];
        }
    }
    __syncthreads();

    // ---- vertical pass + pointwise SSIM ----
    const int tx = tid & 31;
    const int ty = tid >> 5;            // 0..11 (wave = ty pair, uniform NR)
    float lsum = 0.f;

    auto vpart = [&](int rbase, auto nr_tag) {
        constexpr int NR = decltype(nr_tag)::value;
        float vr[4][NR];
#pragma unroll
        for (int q = 0; q < 4; ++q)
#pragma unroll
            for (int j = 0; j < NR; ++j) vr[q][j] = 0.f;
#pragma unroll
        for (int q = 0; q < 4; ++q)
#pragma unroll
            for (int k = 0; k < NR + 10; ++k) {
                float v = hb[q][rbase + k][tx];
#pragma unroll
                for (int j = 0; j < NR; ++j)
                    if (k - j >= 0 && k - j <= 10)
                        vr[q][j] = fmaf(G[k - j], v, vr[q][j]);
            }
#pragma unroll
        for (int j = 0; j < NR; ++j) {
            float mx = vr[0][j], my = vr[1][j];
            float mss = vr[2][j], mxy = vr[3][j];
            float mx2 = mx * mx, my2 = my * my, mxmy = mx * my;
            float num = (2.f * mxmy + 0.0001f) * (2.f * (mxy - mxmy) + 0.0009f);
            float den = (mx2 + my2 + 0.0001f) * ((mss - mx2 - my2) + 0.0009f);
            lsum += num * __builtin_amdgcn_rcpf(den);
        }
    };
    if (ty < 8)
        vpart(3 * ty, std::integral_constant<int, 3>{});          // rows 0..23
    else
        vpart(24 + 2 * (ty - 8), std::integral_constant<int, 2>{}); // rows 24..31

    // ---- block reduction ----
#pragma unroll
    for (int off = 32; off > 0; off >>= 1)
        lsum += __shfl_down(lsum, off, 64);
    if ((tid & 63) == 0) wsum[tid >> 6] = lsum;
    __syncthreads();
    if (tid == 0) {
        float s = 0.f;
#pragma unroll
        for (int w = 0; w < 6; ++w) s += wsum[w];
        atomicAdd(acc, (double)s);
    }
}

__global__ void ssim_finalize_kernel(const double* __restrict__ acc,
                                     float* __restrict__ out)
{
    double mean = acc[0] / NPIX;
    out[0] = (float)(-log10(mean));  // loss
    out[1] = (float)mean;            // ssim_mean
}

extern "C" void kernel_launch(void* const* d_in, const int* in_sizes, int n_in,
                              void* d_out, int out_size, void* d_ws, size_t ws_size,
                              hipStream_t stream)
{
    const float* x = (const float*)d_in[0];
    const float* y = (const float*)d_in[1];
    float* out     = (float*)d_out;
    double* acc    = (double*)d_ws;

    hipMemsetAsync(acc, 0, sizeof(double), stream);

    dim3 grid(IMG / TW, IMG / TH, 48);   // 16 x 16 x 48 = 12288 blocks
    ssim_tile_kernel<<<grid, 384, 0, stream>>>(x, y, acc);
    ssim_finalize_kernel<<<1, 1, 0, stream>>>(acc, out);
}

// Round 5
// 81.744 us; speedup vs baseline: 2.0905x; 2.0905x over previous
//
#include <hip/hip_runtime.h>
#include <math.h>

#define IMG  512
#define TW   32
#define TH   32
#define EXTR 42          // TH + 10 haloed rows
#define HS   33          // hb stride: h-writes & v-reads <=2-way bank alias
#define NBLK 12288       // 16*16*48 tile blocks
#define NPIX 12582912.0  // 48*512*512

// Normalized 11-tap Gaussian, sigma=1.5 — inline literals
constexpr float G[11] = {
    0.00102838f, 0.00759876f, 0.03600077f, 0.10936069f, 0.21300554f,
    0.26601173f,
    0.21300554f, 0.10936069f, 0.03600077f, 0.00759876f, 0.00102838f};

// hb planes: 0=mean(x) 1=mean(y) 2=mean(x^2+y^2) 3=mean(xy)
__global__ __launch_bounds__(384) void ssim_tile_kernel(
    const float* __restrict__ x, const float* __restrict__ y,
    float* __restrict__ partial)
{
    __shared__ float hb[4][EXTR][HS];   // 21.66 KB
    __shared__ float wsum[6];

    const int tid = threadIdx.x;
    const int bx = blockIdx.x, by = blockIdx.y;
    const int c0 = bx * TW, r0 = by * TH;
    const size_t ioff = (size_t)blockIdx.z * IMG * IMG;
    const float* __restrict__ xb = x + ioff;
    const float* __restrict__ yb = y + ioff;

    const bool interior = (bx > 0) & (bx < 15) & (by > 0) & (by < 15);

    // ---- horizontal pass: 42 rows x 8 groups = 336 tasks, one per thread ----
    if (tid < EXTR * 8) {
        const int row = tid >> 3;       // 0..41
        const int g   = tid & 7;        // 4-output col group
        const int gr  = r0 - 5 + row;
        const int gc0 = c0 - 8 + 4 * g; // first of 20 raw cols
        float wx[20], wy[20];
        if (interior) {
            const float* __restrict__ px = xb + gr * IMG + gc0;
            const float* __restrict__ py = yb + gr * IMG + gc0;
#pragma unroll
            for (int i = 0; i < 5; ++i) {
                float4 fx = *(const float4*)(px + 4 * i);
                float4 fy = *(const float4*)(py + 4 * i);
                wx[4*i+0] = fx.x; wx[4*i+1] = fx.y; wx[4*i+2] = fx.z; wx[4*i+3] = fx.w;
                wy[4*i+0] = fy.x; wy[4*i+1] = fy.y; wy[4*i+2] = fy.z; wy[4*i+3] = fy.w;
            }
        } else {
            const bool rok = ((unsigned)gr < IMG);
            const float* __restrict__ px = xb + gr * IMG;
            const float* __restrict__ py = yb + gr * IMG;
#pragma unroll
            for (int i = 0; i < 5; ++i) {
                int gc = gc0 + 4 * i;
                if (rok && gc >= 0 && gc + 3 < IMG) {
                    float4 fx = *(const float4*)(px + gc);
                    float4 fy = *(const float4*)(py + gc);
                    wx[4*i+0] = fx.x; wx[4*i+1] = fx.y; wx[4*i+2] = fx.z; wx[4*i+3] = fx.w;
                    wy[4*i+0] = fy.x; wy[4*i+1] = fy.y; wy[4*i+2] = fy.z; wy[4*i+3] = fy.w;
                } else {
#pragma unroll
                    for (int e = 0; e < 4; ++e) {
                        int c = gc + e;
                        bool ok = rok && ((unsigned)c < IMG);
                        wx[4*i+e] = ok ? px[c] : 0.f;
                        wy[4*i+e] = ok ? py[c] : 0.f;
                    }
                }
            }
        }
        // shared products for raw cols 3..16
        float pss[14], pxy[14];
#pragma unroll
        for (int j = 0; j < 14; ++j) {
            float a = wx[j + 3], b = wy[j + 3];
            pss[j] = fmaf(a, a, b * b);
            pxy[j] = a * b;
        }
        float ax[4] = {}, ay[4] = {}, ass[4] = {}, axy[4] = {};
#pragma unroll
        for (int e = 0; e < 4; ++e)
#pragma unroll
            for (int k = 0; k < 11; ++k) {
                ax[e]  = fmaf(G[k], wx[e + k + 3], ax[e]);
                ay[e]  = fmaf(G[k], wy[e + k + 3], ay[e]);
                ass[e] = fmaf(G[k], pss[e + k], ass[e]);
                axy[e] = fmaf(G[k], pxy[e + k], axy[e]);
            }
#pragma unroll
        for (int e = 0; e < 4; ++e) {
            int cc = 4 * g + e;
            hb[0][row][cc] = ax[e];
            hb[1][row][cc] = ay[e];
            hb[2][row][cc] = ass[e];
            hb[3][row][cc] = axy[e];
        }
    }
    __syncthreads();

    // ---- vertical pass + pointwise SSIM ----
    const int tx = tid & 31;
    const int ty = tid >> 5;            // 0..11 (wave-uniform NR split)
    float lsum = 0.f;

    auto vpart = [&](int rbase, auto nr_tag) {
        constexpr int NR = decltype(nr_tag)::value;
        float vr[4][NR];
#pragma unroll
        for (int q = 0; q < 4; ++q)
#pragma unroll
            for (int j = 0; j < NR; ++j) vr[q][j] = 0.f;
#pragma unroll
        for (int q = 0; q < 4; ++q)
#pragma unroll
            for (int k = 0; k < NR + 10; ++k) {
                float v = hb[q][rbase + k][tx];
#pragma unroll
                for (int j = 0; j < NR; ++j)
                    if (k - j >= 0 && k - j <= 10)
                        vr[q][j] = fmaf(G[k - j], v, vr[q][j]);
            }
#pragma unroll
        for (int j = 0; j < NR; ++j) {
            float mx = vr[0][j], my = vr[1][j];
            float mss = vr[2][j], mxy = vr[3][j];
            float mx2 = mx * mx, my2 = my * my, mxmy = mx * my;
            float num = (2.f * mxmy + 0.0001f) * (2.f * (mxy - mxmy) + 0.0009f);
            float den = (mx2 + my2 + 0.0001f) * ((mss - mx2 - my2) + 0.0009f);
            lsum += num * __builtin_amdgcn_rcpf(den);
        }
    };
    if (ty < 8)
        vpart(3 * ty, std::integral_constant<int, 3>{});            // rows 0..23
    else
        vpart(24 + 2 * (ty - 8), std::integral_constant<int, 2>{}); // rows 24..31

    // ---- block reduction -> plain store (NO global atomic) ----
#pragma unroll
    for (int off = 32; off > 0; off >>= 1)
        lsum += __shfl_down(lsum, off, 64);
    if ((tid & 63) == 0) wsum[tid >> 6] = lsum;
    __syncthreads();
    if (tid == 0) {
        float s = 0.f;
#pragma unroll
        for (int w = 0; w < 6; ++w) s += wsum[w];
        int bid = bx + 16 * (by + 16 * blockIdx.z);
        partial[bid] = s;
    }
}

__global__ __launch_bounds__(1024) void ssim_reduce_kernel(
    const float* __restrict__ partial, float* __restrict__ out)
{
    __shared__ double ws[16];
    const int tid = threadIdx.x;
    double s = 0.0;
    for (int i = tid; i < NBLK; i += 1024) s += (double)partial[i];
#pragma unroll
    for (int off = 32; off > 0; off >>= 1)
        s += __shfl_down(s, off, 64);
    if ((tid & 63) == 0) ws[tid >> 6] = s;
    __syncthreads();
    if (tid == 0) {
        double t = 0.0;
#pragma unroll
        for (int w = 0; w < 16; ++w) t += ws[w];
        double mean = t / NPIX;
        out[0] = (float)(-log10(mean));  // loss
        out[1] = (float)mean;            // ssim_mean
    }
}

extern "C" void kernel_launch(void* const* d_in, const int* in_sizes, int n_in,
                              void* d_out, int out_size, void* d_ws, size_t ws_size,
                              hipStream_t stream)
{
    const float* x = (const float*)d_in[0];
    const float* y = (const float*)d_in[1];
    float* out     = (float*)d_out;
    float* partial = (float*)d_ws;      // 12288 floats, fully rewritten each call

    dim3 grid(IMG / TW, IMG / TH, 48);  // 16 x 16 x 48 = 12288 blocks
    ssim_tile_kernel<<<grid, 384, 0, stream>>>(x, y, partial);
    ssim_reduce_kernel<<<1, 1024, 0, stream>>>(partial, out);
}